// Round 20
// baseline (307.673 us; speedup 1.0000x reference)
//
#include <hip/hip_runtime.h>

#define NN 100000
#define NE 1600000
#define GEMM_GRID 1563            // ceil(NN/64)
#define NBUK 391                  // dst buckets of 256 nodes
#define BCAP 5120                 // per-bucket capacity (mean 4092, +16 sigma)
#define PA_BLOCKS 320             // pass A blocks, 5000 edges each
#define PA_EDGES 5000
#define K1_GRID (16 + PA_BLOCKS)
#define K2_GRID (NBUK + GEMM_GRID)
#define AG1_GRID 6250             // 16 nodes/block (4 waves x 4, wave-independent)
#define AGG2_GRID 12500           // 8 nodes/block (4 waves x 2)

typedef short bf16x8 __attribute__((ext_vector_type(8)));
typedef float f32x4 __attribute__((ext_vector_type(4)));
typedef unsigned int u32;
typedef u32 u32x4 __attribute__((ext_vector_type(4)));
typedef unsigned short u16;

__device__ inline u32 bf16r(float x) {  // RTNE bf16, returns low-16 bits
    u32 u = __float_as_uint(x);
    return (u + 0x7FFFu + ((u >> 16) & 1u)) >> 16;
}

// ---------------- split-bf16 helpers ----------------
__device__ inline void split_pack8(const float a[8], u32 hh[4], u32 ll[4]) {
#pragma unroll
    for (int j = 0; j < 4; ++j) {
        u32 u0 = __float_as_uint(a[2 * j]);
        u32 u1 = __float_as_uint(a[2 * j + 1]);
        float l0 = a[2 * j] - __uint_as_float(u0 & 0xFFFF0000u);
        float l1 = a[2 * j + 1] - __uint_as_float(u1 & 0xFFFF0000u);
        hh[j] = (u0 >> 16) | (u1 & 0xFFFF0000u);
        ll[j] = (__float_as_uint(l0) >> 16) | (__float_as_uint(l1) & 0xFFFF0000u);
    }
}

__device__ inline void wpack_body(int idx, const float* __restrict__ W,
                                  bf16x8* __restrict__ wpH, bf16x8* __restrict__ wpL) {
    if (idx >= 2048) return;
    int lane = idx & 63, tile = idx >> 6;
    int kc = tile >> 3, ct = tile & 7;
    int col = lane & 15, kq = lane >> 4;
    int kbase = kc * 32 + kq * 8;
    float a[8];
#pragma unroll
    for (int i = 0; i < 8; ++i)
        a[i] = W[(size_t)(kbase + i) * 128 + ct * 16 + col];
    u32 hh[4], ll[4];
    split_pack8(a, hh, ll);
    wpH[tile * 64 + lane] = __builtin_bit_cast(bf16x8, (u32x4){hh[0], hh[1], hh[2], hh[3]});
    wpL[tile * 64 + lane] = __builtin_bit_cast(bf16x8, (u32x4){ll[0], ll[1], ll[2], ll[3]});
}

// ---------------- k1: wpack(W1) | wpack(W2) | pass A bucket binning ---------
__global__ __launch_bounds__(256) void k1(
    const float* __restrict__ W1, bf16x8* __restrict__ wpH1, bf16x8* __restrict__ wpL1,
    const float* __restrict__ W2, bf16x8* __restrict__ wpH2, bf16x8* __restrict__ wpL2,
    const int* __restrict__ dst, const int* __restrict__ src,
    int* __restrict__ gtail, u32* __restrict__ tmp) {
    const int b = blockIdx.x;
    if (b < 8) {
        wpack_body(b * 256 + threadIdx.x, W1, wpH1, wpL1);
        return;
    } else if (b < 16) {
        wpack_body((b - 8) * 256 + threadIdx.x, W2, wpH2, wpL2);
        return;
    }
    __shared__ int lhist[NBUK], lcur[NBUK];
    const int t = threadIdx.x;
    const int e0 = (b - 16) * PA_EDGES;
    const int e1 = e0 + PA_EDGES;  // PA_BLOCKS*PA_EDGES == NE exactly
    for (int i = t; i < NBUK; i += 256) lhist[i] = 0;
    __syncthreads();
    for (int e = e0 + t; e < e1; e += 256)
        atomicAdd(&lhist[dst[e] >> 8], 1);
    __syncthreads();
    for (int i = t; i < NBUK; i += 256)
        if (lhist[i] > 0) lcur[i] = atomicAdd(&gtail[i], lhist[i]);
    __syncthreads();
    for (int e = e0 + t; e < e1; e += 256) {
        int d = dst[e];
        int bb = d >> 8;
        int p = atomicAdd(&lcur[bb], 1);
        tmp[(size_t)bb * BCAP + p] = ((u32)(d & 255) << 17) | (u32)src[e];
    }
}

// shared GEMM epilogue (gemm1): h (bf16, node-major) + attention logits
__device__ inline void gemm_epilogue(f32x4 acc[8], int row0, int w, int col, int kq,
                                     const float* __restrict__ atts,
                                     const float* __restrict__ attd,
                                     u16* __restrict__ hb,
                                     float* __restrict__ a_src,
                                     float* __restrict__ a_dst) {
    float as0[4], as1[4], ad0[4], ad1[4];
#pragma unroll
    for (int q = 0; q < 4; ++q) {
        as0[q] = atts[q * 32 + col];
        as1[q] = atts[q * 32 + 16 + col];
        ad0[q] = attd[q * 32 + col];
        ad1[q] = attd[q * 32 + 16 + col];
    }
#pragma unroll
    for (int r = 0; r < 4; ++r) {
        int node = row0 + w * 16 + kq * 4 + r;
        float ps[4], pd[4];
#pragma unroll
        for (int q = 0; q < 4; ++q) {
            float d0 = acc[2 * q][r], d1 = acc[2 * q + 1][r];
            ps[q] = d0 * as0[q] + d1 * as1[q];
            pd[q] = d0 * ad0[q] + d1 * ad1[q];
        }
#pragma unroll
        for (int off = 1; off < 16; off <<= 1) {
#pragma unroll
            for (int q = 0; q < 4; ++q) {
                ps[q] += __shfl_xor(ps[q], off);
                pd[q] += __shfl_xor(pd[q], off);
            }
        }
        if (node < NN) {
#pragma unroll
            for (int ct = 0; ct < 8; ++ct)
                hb[(size_t)node * 128 + ct * 16 + col] = (u16)bf16r(acc[ct][r]);
            if (col < 4) {
                float vs = col == 0 ? ps[0] : col == 1 ? ps[1] : col == 2 ? ps[2] : ps[3];
                float vd = col == 0 ? pd[0] : col == 1 ? pd[1] : col == 2 ? pd[2] : pd[3];
                a_src[node * 4 + col] = vs;
                a_dst[node * 4 + col] = vd;
            }
        }
    }
}

// ---------------- k2: pass B (CSR build in LDS, blocks 0..390) | gemm1 ------
__global__ __launch_bounds__(256) void k2(
    const float* __restrict__ x,
    const bf16x8* __restrict__ wpH, const bf16x8* __restrict__ wpL,
    const float* __restrict__ atts, const float* __restrict__ attd,
    u16* __restrict__ hb, float* __restrict__ a_src, float* __restrict__ a_dst,
    const int* __restrict__ gtail, const u32* __restrict__ tmp,
    int* __restrict__ row_ptr, int* __restrict__ src_sorted) {
    __shared__ u32 ldata[BCAP];     // 20 KB
    __shared__ int lh[256];         // hist -> cursors
    __shared__ int lsc[256];        // scan / reduce workspace
    const int idx = blockIdx.x;
    const int t = threadIdx.x;
    if (idx < NBUK) {
        const int g = idx;
        const int n = gtail[g];
        int acc = 0;
        for (int i = t; i < g; i += 256) acc += gtail[i];
        lsc[t] = acc;
        __syncthreads();
        for (int off = 128; off > 0; off >>= 1) {
            if (t < off) lsc[t] += lsc[t + off];
            __syncthreads();
        }
        const int ebase = lsc[0];
        lh[t] = 0;
        __syncthreads();
        for (int i = t; i < n; i += 256) {
            u32 v = tmp[(size_t)g * BCAP + i];
            ldata[i] = v;
            atomicAdd(&lh[v >> 17], 1);
        }
        __syncthreads();
        int c = lh[t];
        lsc[t] = c;
        __syncthreads();
        for (int off = 1; off < 256; off <<= 1) {
            int xv = (t >= off) ? lsc[t - off] : 0;
            __syncthreads();
            lsc[t] += xv;
            __syncthreads();
        }
        int excl = (t == 0) ? 0 : lsc[t - 1];
        int base = ebase + excl;
        lh[t] = base;
        int node = (g << 8) + t;
        if (node < NN) row_ptr[node] = base;
        if (g == NBUK - 1 && t == 0) row_ptr[NN] = ebase + n;
        __syncthreads();
        for (int i = t; i < n; i += 256) {
            u32 v = ldata[i];
            int p = atomicAdd(&lh[v >> 17], 1);
            src_sorted[p] = (int)(v & 0x1FFFFu);
        }
        return;
    }
    const int row0 = (idx - NBUK) * 64;
    const int lane = t & 63;
    const int w = t >> 6;
    const int col = lane & 15, kq = lane >> 4;
    int node_a = row0 + w * 16 + col;
    if (node_a > NN - 1) node_a = NN - 1;
    const float* xrow = x + (size_t)node_a * 128 + kq * 8;
    float a[32];
#pragma unroll
    for (int kc = 0; kc < 4; ++kc) {
        *(float4*)&a[kc * 8 + 0] = *(const float4*)(xrow + kc * 32);
        *(float4*)&a[kc * 8 + 4] = *(const float4*)(xrow + kc * 32 + 4);
    }
    f32x4 acc[8];
#pragma unroll
    for (int ct = 0; ct < 8; ++ct) acc[ct] = (f32x4){0.f, 0.f, 0.f, 0.f};
#pragma unroll
    for (int kc = 0; kc < 4; ++kc) {
        u32 hh[4], ll[4];
        split_pack8(&a[kc * 8], hh, ll);
        bf16x8 ah = __builtin_bit_cast(bf16x8, (u32x4){hh[0], hh[1], hh[2], hh[3]});
        bf16x8 al = __builtin_bit_cast(bf16x8, (u32x4){ll[0], ll[1], ll[2], ll[3]});
#pragma unroll
        for (int ct = 0; ct < 8; ++ct) {
            bf16x8 bh = wpH[(kc * 8 + ct) * 64 + lane];
            bf16x8 bl = wpL[(kc * 8 + ct) * 64 + lane];
            acc[ct] = __builtin_amdgcn_mfma_f32_16x16x32_bf16(ah, bh, acc[ct], 0, 0, 0);
            acc[ct] = __builtin_amdgcn_mfma_f32_16x16x32_bf16(al, bh, acc[ct], 0, 0, 0);
            acc[ct] = __builtin_amdgcn_mfma_f32_16x16x32_bf16(ah, bl, acc[ct], 0, 0, 0);
        }
    }
    gemm_epilogue(acc, row0, w, col, kq, atts, attd, hb, a_src, a_dst);
}

// ------ k_ag1: agg layer 1 + fused gemm2, WAVE-INDEPENDENT -------------------
// Each wave owns 4 nodes: gather (proven body) -> wave-private LDS rows 0-3
// -> its own 16x16 MFMA tile (rows 4-15 garbage, D rows 4-15 ignored) -> all
// 8 cts for its 4 nodes. No __syncthreads: LDS ops of one wave are
// pipe-ordered; s_waitcnt lgkmcnt(0) + sched_barrier fences the transpose.
__global__ __launch_bounds__(256) void k_ag1(
    const u32* __restrict__ hb,
    const float* __restrict__ a_src, const float* __restrict__ a_dst,
    const int* __restrict__ row_ptr, const int* __restrict__ src_sorted,
    const float* __restrict__ bias1,
    const bf16x8* __restrict__ wpH2, const bf16x8* __restrict__ wpL2,
    const float* __restrict__ atts2, const float* __restrict__ attd2,
    u32* __restrict__ x1b, u16* __restrict__ hb2,
    float* __restrict__ a_src2, float* __restrict__ a_dst2) {
    __shared__ __align__(16) u32 xs[4][16][68];   // per-wave region; rows 0-3 used
    const int t = threadIdx.x;
    const int lane = t & 63;
    const int wv = t >> 6;
    const int q = lane >> 4;
    const int es = lane & 15;
    const int hbase = lane & 48;
    const int node0 = blockIdx.x * 16 + wv * 4;   // NN = 6250*16 exactly
    const float bv0 = bias1[lane * 2], bv1 = bias1[lane * 2 + 1];
    // ---------------- stage 1: aggregate layer 1 (4 nodes) ----------------
#pragma unroll 1
    for (int ni = 0; ni < 4; ++ni) {
        const int node = node0 + ni;
        const int e0 = row_ptr[node], e1 = row_ptr[node + 1];
        const int emax = e1 - 1;
        const float advh = a_dst[node * 4 + q];
        float den = 0.f, a0a = 0.f, a0b = 0.f, a1a = 0.f, a1b = 0.f;
        if (e1 > e0) {
            int eidx = e0 + es;
            if (eidx > emax) eidx = emax;
            int sv = src_sorted[eidx];
            float av = a_src[sv * 4 + q];
            for (int ec = e0; ec < e1; ec += 16) {
                int cnt = e1 - ec;
                cnt = cnt < 16 ? cnt : 16;
                int eidxn = ec + 16 + es;
                if (eidxn > emax) eidxn = emax;
                int svn = src_sorted[eidxn];
                float avn = a_src[svn * 4 + q];
                float lk = av + advh;
                lk = lk > 0.f ? lk : 0.2f * lk;
                float ex = (es < cnt) ? __expf(lk - 8.f) : 0.f;
                den += ex;
                if (cnt == 16) {
                    u32 wvv[16];
#pragma unroll
                    for (int u = 0; u < 16; ++u) {
                        int su = __builtin_amdgcn_readlane(sv, u);
                        wvv[u] = hb[((size_t)su << 6) + lane];
                    }
                    float exu[16];
#pragma unroll
                    for (int u = 0; u < 16; ++u) exu[u] = __shfl(ex, hbase | u);
#pragma unroll
                    for (int u = 0; u < 16; ++u) {
                        float h0 = __uint_as_float(wvv[u] << 16);
                        float h1 = __uint_as_float(wvv[u] & 0xFFFF0000u);
                        if (u & 1) { a0b = fmaf(exu[u], h0, a0b); a1b = fmaf(exu[u], h1, a1b); }
                        else       { a0a = fmaf(exu[u], h0, a0a); a1a = fmaf(exu[u], h1, a1a); }
                    }
                } else {
                    for (int u0 = 0; u0 < cnt; u0 += 4) {
                        u32 wvv[4];
                        float exu[4];
#pragma unroll
                        for (int j = 0; j < 4; ++j) {
                            int su = __builtin_amdgcn_readlane(sv, u0 + j);
                            wvv[j] = hb[((size_t)su << 6) + lane];
                        }
#pragma unroll
                        for (int j = 0; j < 4; ++j) exu[j] = __shfl(ex, hbase | (u0 + j));
#pragma unroll
                        for (int j = 0; j < 4; ++j) {
                            float h0 = __uint_as_float(wvv[j] << 16);
                            float h1 = __uint_as_float(wvv[j] & 0xFFFF0000u);
                            if (j & 1) { a0b = fmaf(exu[j], h0, a0b); a1b = fmaf(exu[j], h1, a1b); }
                            else       { a0a = fmaf(exu[j], h0, a0a); a1a = fmaf(exu[j], h1, a1a); }
                        }
                    }
                }
                sv = svn;
                av = avn;
            }
        }
        float a0 = a0a + a0b, a1 = a1a + a1b;
#pragma unroll
        for (int m = 1; m < 16; m <<= 1) den += __shfl_xor(den, m);
        float inv = den > 0.f ? 1.f / den : 0.f;
        float r0 = fmaxf(fmaf(a0, inv, bv0), 0.f);
        float r1 = fmaxf(fmaf(a1, inv, bv1), 0.f);
        u32 pair = bf16r(r0) | (bf16r(r1) << 16);
        x1b[node * 64 + lane] = pair;
        xs[wv][ni][lane] = pair;
    }
    // fence the wave's own LDS writes before transpose reads (rule #18)
    asm volatile("s_waitcnt lgkmcnt(0)" ::: "memory");
    __builtin_amdgcn_sched_barrier(0);
    // ---------------- stage 2: gemm2 for this wave's 4 nodes ----------------
    const int col = lane & 15, kq = lane >> 4;
    int4 aw[4];
#pragma unroll
    for (int kc = 0; kc < 4; ++kc)
        aw[kc] = *(const int4*)&xs[wv][col & 3][kc * 16 + kq * 4];  // rows 0-3; col>3 dup (D rows garbage unused anyway, but keep in-bounds)
    // A rows: row index = col; we remap col>3 to col&3 -> D rows 4-15 are
    // duplicates of rows 0-3, ignored (only rows 0-3 read below).
    f32x4 acc[8];
#pragma unroll
    for (int ct = 0; ct < 8; ++ct) acc[ct] = (f32x4){0.f, 0.f, 0.f, 0.f};
#pragma unroll
    for (int kc = 0; kc < 4; ++kc) {
        bf16x8 a = __builtin_bit_cast(bf16x8, aw[kc]);
#pragma unroll
        for (int ct = 0; ct < 8; ++ct) {
            acc[ct] = __builtin_amdgcn_mfma_f32_16x16x32_bf16(a, wpH2[(kc * 8 + ct) * 64 + lane], acc[ct], 0, 0, 0);
            acc[ct] = __builtin_amdgcn_mfma_f32_16x16x32_bf16(a, wpL2[(kc * 8 + ct) * 64 + lane], acc[ct], 0, 0, 0);
        }
    }
    float as0[4], as1[4], ad0[4], ad1[4];
#pragma unroll
    for (int qq = 0; qq < 4; ++qq) {
        as0[qq] = atts2[qq * 32 + col];
        as1[qq] = atts2[qq * 32 + 16 + col];
        ad0[qq] = attd2[qq * 32 + col];
        ad1[qq] = attd2[qq * 32 + 16 + col];
    }
#pragma unroll
    for (int r = 0; r < 4; ++r) {
        // node r's outputs live in D row r -> kq==0 lanes
        int node = node0 + r;
        float ps[4], pd[4];
#pragma unroll
        for (int qq = 0; qq < 4; ++qq) {
            float d0 = acc[2 * qq][r], d1 = acc[2 * qq + 1][r];
            ps[qq] = d0 * as0[qq] + d1 * as1[qq];
            pd[qq] = d0 * ad0[qq] + d1 * ad1[qq];
        }
#pragma unroll
        for (int off = 1; off < 16; off <<= 1) {
#pragma unroll
            for (int qq = 0; qq < 4; ++qq) {
                ps[qq] += __shfl_xor(ps[qq], off);
                pd[qq] += __shfl_xor(pd[qq], off);
            }
        }
        if (kq == 0) {
#pragma unroll
            for (int ct = 0; ct < 8; ++ct)
                hb2[(size_t)node * 128 + ct * 16 + col] = (u16)bf16r(acc[ct][r]);
            if (col < 4) {
                float vs = col == 0 ? ps[0] : col == 1 ? ps[1] : col == 2 ? ps[2] : ps[3];
                float vd = col == 0 ? pd[0] : col == 1 ? pd[1] : col == 2 ? pd[2] : pd[3];
                a_src2[node * 4 + col] = vs;
                a_dst2[node * 4 + col] = vd;
            }
        }
    }
}

// ---------------- k_agg2: layer-2 aggregation (r16 proven body) --------------
__global__ __launch_bounds__(256, 4) void k_agg2(
    const u32* __restrict__ hb,
    const float* __restrict__ a_src, const float* __restrict__ a_dst,
    const int* __restrict__ row_ptr, const int* __restrict__ src_sorted,
    const float* __restrict__ bias,
    const u32* __restrict__ x1b, float* __restrict__ outp) {
    const int lane = threadIdx.x & 63;
    const int node0 = blockIdx.x * 8 + (threadIdx.x >> 6) * 2;
    const int q = lane >> 4;
    const int es = lane & 15;
    const int hbase = lane & 48;
#pragma unroll
    for (int ni = 0; ni < 2; ++ni) {
        const int node = node0 + ni;
        if (node >= NN) continue;
        const int e0 = row_ptr[node], e1 = row_ptr[node + 1];
        const int emax = e1 - 1;
        const float advh = a_dst[node * 4 + q];
        float den = 0.f, a0a = 0.f, a0b = 0.f, a1a = 0.f, a1b = 0.f;
        if (e1 > e0) {
            int eidx = e0 + es;
            if (eidx > emax) eidx = emax;
            int sv = src_sorted[eidx];
            float av = a_src[sv * 4 + q];
            for (int ec = e0; ec < e1; ec += 16) {
                int cnt = e1 - ec;
                cnt = cnt < 16 ? cnt : 16;
                int eidxn = ec + 16 + es;
                if (eidxn > emax) eidxn = emax;
                int svn = src_sorted[eidxn];
                float avn = a_src[svn * 4 + q];
                float lk = av + advh;
                lk = lk > 0.f ? lk : 0.2f * lk;
                float ex = (es < cnt) ? __expf(lk - 8.f) : 0.f;
                den += ex;
                if (cnt == 16) {
                    u32 wv[16];
#pragma unroll
                    for (int u = 0; u < 16; ++u) {
                        int su = __builtin_amdgcn_readlane(sv, u);
                        wv[u] = hb[((size_t)su << 6) + lane];
                    }
                    float exu[16];
#pragma unroll
                    for (int u = 0; u < 16; ++u) exu[u] = __shfl(ex, hbase | u);
#pragma unroll
                    for (int u = 0; u < 16; ++u) {
                        float h0 = __uint_as_float(wv[u] << 16);
                        float h1 = __uint_as_float(wv[u] & 0xFFFF0000u);
                        if (u & 1) { a0b = fmaf(exu[u], h0, a0b); a1b = fmaf(exu[u], h1, a1b); }
                        else       { a0a = fmaf(exu[u], h0, a0a); a1a = fmaf(exu[u], h1, a1a); }
                    }
                } else {
                    for (int u0 = 0; u0 < cnt; u0 += 4) {
                        u32 wv[4];
                        float exu[4];
#pragma unroll
                        for (int j = 0; j < 4; ++j) {
                            int su = __builtin_amdgcn_readlane(sv, u0 + j);
                            wv[j] = hb[((size_t)su << 6) + lane];
                        }
#pragma unroll
                        for (int j = 0; j < 4; ++j) exu[j] = __shfl(ex, hbase | (u0 + j));
#pragma unroll
                        for (int j = 0; j < 4; ++j) {
                            float h0 = __uint_as_float(wv[j] << 16);
                            float h1 = __uint_as_float(wv[j] & 0xFFFF0000u);
                            if (j & 1) { a0b = fmaf(exu[j], h0, a0b); a1b = fmaf(exu[j], h1, a1b); }
                            else       { a0a = fmaf(exu[j], h0, a0a); a1a = fmaf(exu[j], h1, a1a); }
                        }
                    }
                }
                sv = svn;
                av = avn;
            }
        }
        float a0 = a0a + a0b, a1 = a1a + a1b;
#pragma unroll
        for (int m = 1; m < 16; m <<= 1) den += __shfl_xor(den, m);
        float inv = den > 0.f ? 1.f / den : 0.f;
        int c0 = lane * 2;
        float r0 = fmaxf(fmaf(a0, inv, bias[c0]), 0.f);
        float r1 = fmaxf(fmaf(a1, inv, bias[c0 + 1]), 0.f);
        u32 w1 = x1b[node * 64 + lane];
        float4 o;
        o.x = __uint_as_float(w1 << 16);          // x1[2l]
        o.y = r0;                                  // x2[2l]
        o.z = __uint_as_float(w1 & 0xFFFF0000u);  // x1[2l+1]
        o.w = r1;                                  // x2[2l+1]
        u32x4 ov = __builtin_bit_cast(u32x4, o);
        __builtin_nontemporal_store(ov,
            (u32x4*)(outp + (size_t)node * 256 + lane * 4));
    }
}

// ---------------- launch ----------------

extern "C" void kernel_launch(void* const* d_in, const int* in_sizes, int n_in,
                              void* d_out, int out_size, void* d_ws, size_t ws_size,
                              hipStream_t stream) {
    const float* x   = (const float*)d_in[0];
    const int*   ei  = (const int*)d_in[1];
    const float* W1  = (const float*)d_in[2];
    const float* as1 = (const float*)d_in[3];
    const float* ad1 = (const float*)d_in[4];
    const float* b1  = (const float*)d_in[5];
    const float* W2  = (const float*)d_in[6];
    const float* as2 = (const float*)d_in[7];
    const float* ad2 = (const float*)d_in[8];
    const float* b2  = (const float*)d_in[9];
    float* out = (float*)d_out;
    const int* src = ei;
    const int* dst = ei + NE;

    char* w = (char*)d_ws;
    size_t off = 0;
    auto alloc = [&](size_t bytes) -> void* {
        void* p = w + off;
        off = (off + bytes + 255) & ~((size_t)255);
        return p;
    };
    u16* hb         = (u16*)alloc((size_t)NN * 128 * 2);   // layer-1 h (bf16)
    u16* hb2        = (u16*)alloc((size_t)NN * 128 * 2);   // layer-2 h (bf16)
    u32* x1b        = (u32*)alloc((size_t)NN * 64 * 4);    // x1 as bf16 pairs
    float* a_src    = (float*)alloc((size_t)NN * 4 * 4);
    float* a_dst    = (float*)alloc((size_t)NN * 4 * 4);
    float* a_src2   = (float*)alloc((size_t)NN * 4 * 4);
    float* a_dst2   = (float*)alloc((size_t)NN * 4 * 4);
    int* row_ptr    = (int*)alloc((size_t)(NN + 1) * 4);
    int* gtail      = (int*)alloc(NBUK * 4);
    u32* tmp        = (u32*)alloc((size_t)NBUK * BCAP * 4);
    int* src_sorted = (int*)alloc((size_t)NE * 4);
    bf16x8* wpH1    = (bf16x8*)alloc(2048 * 16);
    bf16x8* wpL1    = (bf16x8*)alloc(2048 * 16);
    bf16x8* wpH2    = (bf16x8*)alloc(2048 * 16);
    bf16x8* wpL2    = (bf16x8*)alloc(2048 * 16);

    (void)hipMemsetAsync(gtail, 0, NBUK * 4, stream);
    // wpack(W1) | wpack(W2) | pass A bucket binning
    k1<<<K1_GRID, 256, 0, stream>>>(W1, wpH1, wpL1, W2, wpH2, wpL2,
                                    dst, src, gtail, tmp);
    // pass B (CSR in LDS) | gemm1
    k2<<<K2_GRID, 256, 0, stream>>>(x, wpH1, wpL1, as1, ad1, hb, a_src, a_dst,
                                    gtail, tmp, row_ptr, src_sorted);
    // agg layer 1 + fused gemm2 (wave-independent)
    k_ag1<<<AG1_GRID, 256, 0, stream>>>((const u32*)hb, a_src, a_dst, row_ptr,
                                        src_sorted, b1, wpH2, wpL2, as2, ad2,
                                        x1b, hb2, a_src2, a_dst2);
    // agg layer 2 -> final interleaved output
    k_agg2<<<AGG2_GRID, 256, 0, stream>>>((const u32*)hb2, a_src2, a_dst2,
                                          row_ptr, src_sorted, b2,
                                          (const u32*)x1b, out);
}

// Round 21
// 267.132 us; speedup vs baseline: 1.1518x; 1.1518x over previous
//
#include <hip/hip_runtime.h>

#define NN 100000
#define NE 1600000
#define GEMM_GRID 1563            // ceil(NN/64)
#define NBUK 391                  // dst buckets of 256 nodes
#define BCAP 5120                 // per-bucket capacity (mean 4092, +16 sigma)
#define PA_BLOCKS 320             // pass A blocks, 5000 edges each
#define PA_EDGES 5000
#define K1_GRID (16 + PA_BLOCKS)
#define K2_GRID (NBUK + GEMM_GRID)
#define AG1_GRID 12500            // 8 nodes/block (2 waves x 4)
#define AGG2_GRID 12500           // 8 nodes/block (4 waves x 2)

typedef short bf16x8 __attribute__((ext_vector_type(8)));
typedef float f32x4 __attribute__((ext_vector_type(4)));
typedef unsigned int u32;
typedef u32 u32x4 __attribute__((ext_vector_type(4)));
typedef unsigned short u16;

__device__ inline u32 bf16r(float x) {  // RTNE bf16, returns low-16 bits
    u32 u = __float_as_uint(x);
    return (u + 0x7FFFu + ((u >> 16) & 1u)) >> 16;
}

// ---------------- split-bf16 helpers ----------------
__device__ inline void split_pack8(const float a[8], u32 hh[4], u32 ll[4]) {
#pragma unroll
    for (int j = 0; j < 4; ++j) {
        u32 u0 = __float_as_uint(a[2 * j]);
        u32 u1 = __float_as_uint(a[2 * j + 1]);
        float l0 = a[2 * j] - __uint_as_float(u0 & 0xFFFF0000u);
        float l1 = a[2 * j + 1] - __uint_as_float(u1 & 0xFFFF0000u);
        hh[j] = (u0 >> 16) | (u1 & 0xFFFF0000u);
        ll[j] = (__float_as_uint(l0) >> 16) | (__float_as_uint(l1) & 0xFFFF0000u);
    }
}

__device__ inline void wpack_body(int idx, const float* __restrict__ W,
                                  bf16x8* __restrict__ wpH, bf16x8* __restrict__ wpL) {
    if (idx >= 2048) return;
    int lane = idx & 63, tile = idx >> 6;
    int kc = tile >> 3, ct = tile & 7;
    int col = lane & 15, kq = lane >> 4;
    int kbase = kc * 32 + kq * 8;
    float a[8];
#pragma unroll
    for (int i = 0; i < 8; ++i)
        a[i] = W[(size_t)(kbase + i) * 128 + ct * 16 + col];
    u32 hh[4], ll[4];
    split_pack8(a, hh, ll);
    wpH[tile * 64 + lane] = __builtin_bit_cast(bf16x8, (u32x4){hh[0], hh[1], hh[2], hh[3]});
    wpL[tile * 64 + lane] = __builtin_bit_cast(bf16x8, (u32x4){ll[0], ll[1], ll[2], ll[3]});
}

// ---------------- k1: wpack(W1) | wpack(W2) | pass A bucket binning ---------
__global__ __launch_bounds__(256) void k1(
    const float* __restrict__ W1, bf16x8* __restrict__ wpH1, bf16x8* __restrict__ wpL1,
    const float* __restrict__ W2, bf16x8* __restrict__ wpH2, bf16x8* __restrict__ wpL2,
    const int* __restrict__ dst, const int* __restrict__ src,
    int* __restrict__ gtail, u32* __restrict__ tmp) {
    const int b = blockIdx.x;
    if (b < 8) {
        wpack_body(b * 256 + threadIdx.x, W1, wpH1, wpL1);
        return;
    } else if (b < 16) {
        wpack_body((b - 8) * 256 + threadIdx.x, W2, wpH2, wpL2);
        return;
    }
    __shared__ int lhist[NBUK], lcur[NBUK];
    const int t = threadIdx.x;
    const int e0 = (b - 16) * PA_EDGES;
    const int e1 = e0 + PA_EDGES;  // PA_BLOCKS*PA_EDGES == NE exactly
    for (int i = t; i < NBUK; i += 256) lhist[i] = 0;
    __syncthreads();
    for (int e = e0 + t; e < e1; e += 256)
        atomicAdd(&lhist[dst[e] >> 8], 1);
    __syncthreads();
    for (int i = t; i < NBUK; i += 256)
        if (lhist[i] > 0) lcur[i] = atomicAdd(&gtail[i], lhist[i]);
    __syncthreads();
    for (int e = e0 + t; e < e1; e += 256) {
        int d = dst[e];
        int bb = d >> 8;
        int p = atomicAdd(&lcur[bb], 1);
        tmp[(size_t)bb * BCAP + p] = ((u32)(d & 255) << 17) | (u32)src[e];
    }
}

// shared GEMM epilogue (gemm1): h (bf16, node-major) + attention logits
__device__ inline void gemm_epilogue(f32x4 acc[8], int row0, int w, int col, int kq,
                                     const float* __restrict__ atts,
                                     const float* __restrict__ attd,
                                     u16* __restrict__ hb,
                                     float* __restrict__ a_src,
                                     float* __restrict__ a_dst) {
    float as0[4], as1[4], ad0[4], ad1[4];
#pragma unroll
    for (int q = 0; q < 4; ++q) {
        as0[q] = atts[q * 32 + col];
        as1[q] = atts[q * 32 + 16 + col];
        ad0[q] = attd[q * 32 + col];
        ad1[q] = attd[q * 32 + 16 + col];
    }
#pragma unroll
    for (int r = 0; r < 4; ++r) {
        int node = row0 + w * 16 + kq * 4 + r;
        float ps[4], pd[4];
#pragma unroll
        for (int q = 0; q < 4; ++q) {
            float d0 = acc[2 * q][r], d1 = acc[2 * q + 1][r];
            ps[q] = d0 * as0[q] + d1 * as1[q];
            pd[q] = d0 * ad0[q] + d1 * ad1[q];
        }
#pragma unroll
        for (int off = 1; off < 16; off <<= 1) {
#pragma unroll
            for (int q = 0; q < 4; ++q) {
                ps[q] += __shfl_xor(ps[q], off);
                pd[q] += __shfl_xor(pd[q], off);
            }
        }
        if (node < NN) {
#pragma unroll
            for (int ct = 0; ct < 8; ++ct)
                hb[(size_t)node * 128 + ct * 16 + col] = (u16)bf16r(acc[ct][r]);
            if (col < 4) {
                float vs = col == 0 ? ps[0] : col == 1 ? ps[1] : col == 2 ? ps[2] : ps[3];
                float vd = col == 0 ? pd[0] : col == 1 ? pd[1] : col == 2 ? pd[2] : pd[3];
                a_src[node * 4 + col] = vs;
                a_dst[node * 4 + col] = vd;
            }
        }
    }
}

// ---------------- k2: pass B (CSR build in LDS, blocks 0..390) | gemm1 ------
__global__ __launch_bounds__(256) void k2(
    const float* __restrict__ x,
    const bf16x8* __restrict__ wpH, const bf16x8* __restrict__ wpL,
    const float* __restrict__ atts, const float* __restrict__ attd,
    u16* __restrict__ hb, float* __restrict__ a_src, float* __restrict__ a_dst,
    const int* __restrict__ gtail, const u32* __restrict__ tmp,
    int* __restrict__ row_ptr, int* __restrict__ src_sorted) {
    __shared__ u32 ldata[BCAP];     // 20 KB
    __shared__ int lh[256];         // hist -> cursors
    __shared__ int lsc[256];        // scan / reduce workspace
    const int idx = blockIdx.x;
    const int t = threadIdx.x;
    if (idx < NBUK) {
        const int g = idx;
        const int n = gtail[g];
        int acc = 0;
        for (int i = t; i < g; i += 256) acc += gtail[i];
        lsc[t] = acc;
        __syncthreads();
        for (int off = 128; off > 0; off >>= 1) {
            if (t < off) lsc[t] += lsc[t + off];
            __syncthreads();
        }
        const int ebase = lsc[0];
        lh[t] = 0;
        __syncthreads();
        for (int i = t; i < n; i += 256) {
            u32 v = tmp[(size_t)g * BCAP + i];
            ldata[i] = v;
            atomicAdd(&lh[v >> 17], 1);
        }
        __syncthreads();
        int c = lh[t];
        lsc[t] = c;
        __syncthreads();
        for (int off = 1; off < 256; off <<= 1) {
            int xv = (t >= off) ? lsc[t - off] : 0;
            __syncthreads();
            lsc[t] += xv;
            __syncthreads();
        }
        int excl = (t == 0) ? 0 : lsc[t - 1];
        int base = ebase + excl;
        lh[t] = base;
        int node = (g << 8) + t;
        if (node < NN) row_ptr[node] = base;
        if (g == NBUK - 1 && t == 0) row_ptr[NN] = ebase + n;
        __syncthreads();
        for (int i = t; i < n; i += 256) {
            u32 v = ldata[i];
            int p = atomicAdd(&lh[v >> 17], 1);
            src_sorted[p] = (int)(v & 0x1FFFFu);
        }
        return;
    }
    const int row0 = (idx - NBUK) * 64;
    const int lane = t & 63;
    const int w = t >> 6;
    const int col = lane & 15, kq = lane >> 4;
    int node_a = row0 + w * 16 + col;
    if (node_a > NN - 1) node_a = NN - 1;
    const float* xrow = x + (size_t)node_a * 128 + kq * 8;
    float a[32];
#pragma unroll
    for (int kc = 0; kc < 4; ++kc) {
        *(float4*)&a[kc * 8 + 0] = *(const float4*)(xrow + kc * 32);
        *(float4*)&a[kc * 8 + 4] = *(const float4*)(xrow + kc * 32 + 4);
    }
    f32x4 acc[8];
#pragma unroll
    for (int ct = 0; ct < 8; ++ct) acc[ct] = (f32x4){0.f, 0.f, 0.f, 0.f};
#pragma unroll
    for (int kc = 0; kc < 4; ++kc) {
        u32 hh[4], ll[4];
        split_pack8(&a[kc * 8], hh, ll);
        bf16x8 ah = __builtin_bit_cast(bf16x8, (u32x4){hh[0], hh[1], hh[2], hh[3]});
        bf16x8 al = __builtin_bit_cast(bf16x8, (u32x4){ll[0], ll[1], ll[2], ll[3]});
#pragma unroll
        for (int ct = 0; ct < 8; ++ct) {
            bf16x8 bh = wpH[(kc * 8 + ct) * 64 + lane];
            bf16x8 bl = wpL[(kc * 8 + ct) * 64 + lane];
            acc[ct] = __builtin_amdgcn_mfma_f32_16x16x32_bf16(ah, bh, acc[ct], 0, 0, 0);
            acc[ct] = __builtin_amdgcn_mfma_f32_16x16x32_bf16(al, bh, acc[ct], 0, 0, 0);
            acc[ct] = __builtin_amdgcn_mfma_f32_16x16x32_bf16(ah, bl, acc[ct], 0, 0, 0);
        }
    }
    gemm_epilogue(acc, row0, w, col, kq, atts, attd, hb, a_src, a_dst);
}

// ------ k_ag1: agg layer 1 (2 waves x 4 nodes) + fused gemm2 (8-row tile) ----
// Stage 1: proven gather body (4 nodes/wave) -> xs rows 0-7. One barrier
// (couples only 2 waves -> small tail). Stage 2: 8-valid-row MFMA tile;
// wave w computes cts {4w..4w+3} = heads {2w, 2w+1} with acc[4] (16 VGPR).
__global__ __launch_bounds__(128) void k_ag1(
    const u32* __restrict__ hb,
    const float* __restrict__ a_src, const float* __restrict__ a_dst,
    const int* __restrict__ row_ptr, const int* __restrict__ src_sorted,
    const float* __restrict__ bias1,
    const bf16x8* __restrict__ wpH2, const bf16x8* __restrict__ wpL2,
    const float* __restrict__ atts2, const float* __restrict__ attd2,
    u32* __restrict__ x1b, u16* __restrict__ hb2,
    float* __restrict__ a_src2, float* __restrict__ a_dst2) {
    __shared__ __align__(16) u32 xs[8][68];
    const int t = threadIdx.x;
    const int lane = t & 63;
    const int wv = t >> 6;            // 0 or 1
    const int q = lane >> 4;
    const int es = lane & 15;
    const int hbase = lane & 48;
    const int node0 = blockIdx.x * 8;  // NN = 12500*8 exactly
    const float bv0 = bias1[lane * 2], bv1 = bias1[lane * 2 + 1];
    // ---------------- stage 1: aggregate layer 1 (4 nodes per wave) ---------
#pragma unroll 1
    for (int ni = 0; ni < 4; ++ni) {
        const int node = node0 + wv * 4 + ni;
        const int e0 = row_ptr[node], e1 = row_ptr[node + 1];
        const int emax = e1 - 1;
        const float advh = a_dst[node * 4 + q];
        float den = 0.f, a0a = 0.f, a0b = 0.f, a1a = 0.f, a1b = 0.f;
        if (e1 > e0) {
            int eidx = e0 + es;
            if (eidx > emax) eidx = emax;
            int sv = src_sorted[eidx];
            float av = a_src[sv * 4 + q];
            for (int ec = e0; ec < e1; ec += 16) {
                int cnt = e1 - ec;
                cnt = cnt < 16 ? cnt : 16;
                int eidxn = ec + 16 + es;
                if (eidxn > emax) eidxn = emax;
                int svn = src_sorted[eidxn];
                float avn = a_src[svn * 4 + q];
                float lk = av + advh;
                lk = lk > 0.f ? lk : 0.2f * lk;
                float ex = (es < cnt) ? __expf(lk - 8.f) : 0.f;
                den += ex;
                if (cnt == 16) {
                    u32 wvv[16];
#pragma unroll
                    for (int u = 0; u < 16; ++u) {
                        int su = __builtin_amdgcn_readlane(sv, u);
                        wvv[u] = hb[((size_t)su << 6) + lane];
                    }
                    float exu[16];
#pragma unroll
                    for (int u = 0; u < 16; ++u) exu[u] = __shfl(ex, hbase | u);
#pragma unroll
                    for (int u = 0; u < 16; ++u) {
                        float h0 = __uint_as_float(wvv[u] << 16);
                        float h1 = __uint_as_float(wvv[u] & 0xFFFF0000u);
                        if (u & 1) { a0b = fmaf(exu[u], h0, a0b); a1b = fmaf(exu[u], h1, a1b); }
                        else       { a0a = fmaf(exu[u], h0, a0a); a1a = fmaf(exu[u], h1, a1a); }
                    }
                } else {
                    for (int u0 = 0; u0 < cnt; u0 += 4) {
                        u32 wvv[4];
                        float exu[4];
#pragma unroll
                        for (int j = 0; j < 4; ++j) {
                            int su = __builtin_amdgcn_readlane(sv, u0 + j);
                            wvv[j] = hb[((size_t)su << 6) + lane];
                        }
#pragma unroll
                        for (int j = 0; j < 4; ++j) exu[j] = __shfl(ex, hbase | (u0 + j));
#pragma unroll
                        for (int j = 0; j < 4; ++j) {
                            float h0 = __uint_as_float(wvv[j] << 16);
                            float h1 = __uint_as_float(wvv[j] & 0xFFFF0000u);
                            if (j & 1) { a0b = fmaf(exu[j], h0, a0b); a1b = fmaf(exu[j], h1, a1b); }
                            else       { a0a = fmaf(exu[j], h0, a0a); a1a = fmaf(exu[j], h1, a1a); }
                        }
                    }
                }
                sv = svn;
                av = avn;
            }
        }
        float a0 = a0a + a0b, a1 = a1a + a1b;
#pragma unroll
        for (int m = 1; m < 16; m <<= 1) den += __shfl_xor(den, m);
        float inv = den > 0.f ? 1.f / den : 0.f;
        float r0 = fmaxf(fmaf(a0, inv, bv0), 0.f);
        float r1 = fmaxf(fmaf(a1, inv, bv1), 0.f);
        u32 pair = bf16r(r0) | (bf16r(r1) << 16);
        x1b[node * 64 + lane] = pair;
        xs[wv * 4 + ni][lane] = pair;
    }
    __syncthreads();
    // ---------------- stage 2: gemm2 for the block's 8 nodes ----------------
    const int col = lane & 15, kq = lane >> 4;
    int4 aw[4];
#pragma unroll
    for (int kc = 0; kc < 4; ++kc)
        aw[kc] = *(const int4*)&xs[col & 7][kc * 16 + kq * 4];  // rows 8-15 dup, ignored
    f32x4 acc[4];
#pragma unroll
    for (int c = 0; c < 4; ++c) acc[c] = (f32x4){0.f, 0.f, 0.f, 0.f};
#pragma unroll
    for (int kc = 0; kc < 4; ++kc) {
        bf16x8 a = __builtin_bit_cast(bf16x8, aw[kc]);
#pragma unroll
        for (int c = 0; c < 4; ++c) {
            int ct = wv * 4 + c;
            acc[c] = __builtin_amdgcn_mfma_f32_16x16x32_bf16(a, wpH2[(kc * 8 + ct) * 64 + lane], acc[c], 0, 0, 0);
            acc[c] = __builtin_amdgcn_mfma_f32_16x16x32_bf16(a, wpL2[(kc * 8 + ct) * 64 + lane], acc[c], 0, 0, 0);
        }
    }
    float as0[2], as1[2], ad0[2], ad1[2];
#pragma unroll
    for (int qq = 0; qq < 2; ++qq) {
        int hq = 2 * wv + qq;
        as0[qq] = atts2[hq * 32 + col];
        as1[qq] = atts2[hq * 32 + 16 + col];
        ad0[qq] = attd2[hq * 32 + col];
        ad1[qq] = attd2[hq * 32 + 16 + col];
    }
#pragma unroll
    for (int r = 0; r < 4; ++r) {
        int rr = kq * 4 + r;              // D row; valid node if rr < 8 (kq < 2)
        int node = node0 + rr;
        float ps[2], pd[2];
#pragma unroll
        for (int qq = 0; qq < 2; ++qq) {
            float d0 = acc[2 * qq][r], d1 = acc[2 * qq + 1][r];
            ps[qq] = d0 * as0[qq] + d1 * as1[qq];
            pd[qq] = d0 * ad0[qq] + d1 * ad1[qq];
        }
#pragma unroll
        for (int off = 1; off < 16; off <<= 1) {
#pragma unroll
            for (int qq = 0; qq < 2; ++qq) {
                ps[qq] += __shfl_xor(ps[qq], off);
                pd[qq] += __shfl_xor(pd[qq], off);
            }
        }
        if (kq < 2) {
#pragma unroll
            for (int c = 0; c < 4; ++c)
                hb2[(size_t)node * 128 + (wv * 4 + c) * 16 + col] = (u16)bf16r(acc[c][r]);
            if (col < 2) {
                int hq = 2 * wv + col;
                a_src2[node * 4 + hq] = col == 0 ? ps[0] : ps[1];
                a_dst2[node * 4 + hq] = col == 0 ? pd[0] : pd[1];
            }
        }
    }
}

// ---------------- k_agg2: layer-2 aggregation (r16 proven body) --------------
__global__ __launch_bounds__(256, 4) void k_agg2(
    const u32* __restrict__ hb,
    const float* __restrict__ a_src, const float* __restrict__ a_dst,
    const int* __restrict__ row_ptr, const int* __restrict__ src_sorted,
    const float* __restrict__ bias,
    const u32* __restrict__ x1b, float* __restrict__ outp) {
    const int lane = threadIdx.x & 63;
    const int node0 = blockIdx.x * 8 + (threadIdx.x >> 6) * 2;
    const int q = lane >> 4;
    const int es = lane & 15;
    const int hbase = lane & 48;
#pragma unroll
    for (int ni = 0; ni < 2; ++ni) {
        const int node = node0 + ni;
        if (node >= NN) continue;
        const int e0 = row_ptr[node], e1 = row_ptr[node + 1];
        const int emax = e1 - 1;
        const float advh = a_dst[node * 4 + q];
        float den = 0.f, a0a = 0.f, a0b = 0.f, a1a = 0.f, a1b = 0.f;
        if (e1 > e0) {
            int eidx = e0 + es;
            if (eidx > emax) eidx = emax;
            int sv = src_sorted[eidx];
            float av = a_src[sv * 4 + q];
            for (int ec = e0; ec < e1; ec += 16) {
                int cnt = e1 - ec;
                cnt = cnt < 16 ? cnt : 16;
                int eidxn = ec + 16 + es;
                if (eidxn > emax) eidxn = emax;
                int svn = src_sorted[eidxn];
                float avn = a_src[svn * 4 + q];
                float lk = av + advh;
                lk = lk > 0.f ? lk : 0.2f * lk;
                float ex = (es < cnt) ? __expf(lk - 8.f) : 0.f;
                den += ex;
                if (cnt == 16) {
                    u32 wv[16];
#pragma unroll
                    for (int u = 0; u < 16; ++u) {
                        int su = __builtin_amdgcn_readlane(sv, u);
                        wv[u] = hb[((size_t)su << 6) + lane];
                    }
                    float exu[16];
#pragma unroll
                    for (int u = 0; u < 16; ++u) exu[u] = __shfl(ex, hbase | u);
#pragma unroll
                    for (int u = 0; u < 16; ++u) {
                        float h0 = __uint_as_float(wv[u] << 16);
                        float h1 = __uint_as_float(wv[u] & 0xFFFF0000u);
                        if (u & 1) { a0b = fmaf(exu[u], h0, a0b); a1b = fmaf(exu[u], h1, a1b); }
                        else       { a0a = fmaf(exu[u], h0, a0a); a1a = fmaf(exu[u], h1, a1a); }
                    }
                } else {
                    for (int u0 = 0; u0 < cnt; u0 += 4) {
                        u32 wv[4];
                        float exu[4];
#pragma unroll
                        for (int j = 0; j < 4; ++j) {
                            int su = __builtin_amdgcn_readlane(sv, u0 + j);
                            wv[j] = hb[((size_t)su << 6) + lane];
                        }
#pragma unroll
                        for (int j = 0; j < 4; ++j) exu[j] = __shfl(ex, hbase | (u0 + j));
#pragma unroll
                        for (int j = 0; j < 4; ++j) {
                            float h0 = __uint_as_float(wv[j] << 16);
                            float h1 = __uint_as_float(wv[j] & 0xFFFF0000u);
                            if (j & 1) { a0b = fmaf(exu[j], h0, a0b); a1b = fmaf(exu[j], h1, a1b); }
                            else       { a0a = fmaf(exu[j], h0, a0a); a1a = fmaf(exu[j], h1, a1a); }
                        }
                    }
                }
                sv = svn;
                av = avn;
            }
        }
        float a0 = a0a + a0b, a1 = a1a + a1b;
#pragma unroll
        for (int m = 1; m < 16; m <<= 1) den += __shfl_xor(den, m);
        float inv = den > 0.f ? 1.f / den : 0.f;
        int c0 = lane * 2;
        float r0 = fmaxf(fmaf(a0, inv, bias[c0]), 0.f);
        float r1 = fmaxf(fmaf(a1, inv, bias[c0 + 1]), 0.f);
        u32 w1 = x1b[node * 64 + lane];
        float4 o;
        o.x = __uint_as_float(w1 << 16);          // x1[2l]
        o.y = r0;                                  // x2[2l]
        o.z = __uint_as_float(w1 & 0xFFFF0000u);  // x1[2l+1]
        o.w = r1;                                  // x2[2l+1]
        u32x4 ov = __builtin_bit_cast(u32x4, o);
        __builtin_nontemporal_store(ov,
            (u32x4*)(outp + (size_t)node * 256 + lane * 4));
    }
}

// ---------------- launch ----------------

extern "C" void kernel_launch(void* const* d_in, const int* in_sizes, int n_in,
                              void* d_out, int out_size, void* d_ws, size_t ws_size,
                              hipStream_t stream) {
    const float* x   = (const float*)d_in[0];
    const int*   ei  = (const int*)d_in[1];
    const float* W1  = (const float*)d_in[2];
    const float* as1 = (const float*)d_in[3];
    const float* ad1 = (const float*)d_in[4];
    const float* b1  = (const float*)d_in[5];
    const float* W2  = (const float*)d_in[6];
    const float* as2 = (const float*)d_in[7];
    const float* ad2 = (const float*)d_in[8];
    const float* b2  = (const float*)d_in[9];
    float* out = (float*)d_out;
    const int* src = ei;
    const int* dst = ei + NE;

    char* w = (char*)d_ws;
    size_t off = 0;
    auto alloc = [&](size_t bytes) -> void* {
        void* p = w + off;
        off = (off + bytes + 255) & ~((size_t)255);
        return p;
    };
    u16* hb         = (u16*)alloc((size_t)NN * 128 * 2);   // layer-1 h (bf16)
    u16* hb2        = (u16*)alloc((size_t)NN * 128 * 2);   // layer-2 h (bf16)
    u32* x1b        = (u32*)alloc((size_t)NN * 64 * 4);    // x1 as bf16 pairs
    float* a_src    = (float*)alloc((size_t)NN * 4 * 4);
    float* a_dst    = (float*)alloc((size_t)NN * 4 * 4);
    float* a_src2   = (float*)alloc((size_t)NN * 4 * 4);
    float* a_dst2   = (float*)alloc((size_t)NN * 4 * 4);
    int* row_ptr    = (int*)alloc((size_t)(NN + 1) * 4);
    int* gtail      = (int*)alloc(NBUK * 4);
    u32* tmp        = (u32*)alloc((size_t)NBUK * BCAP * 4);
    int* src_sorted = (int*)alloc((size_t)NE * 4);
    bf16x8* wpH1    = (bf16x8*)alloc(2048 * 16);
    bf16x8* wpL1    = (bf16x8*)alloc(2048 * 16);
    bf16x8* wpH2    = (bf16x8*)alloc(2048 * 16);
    bf16x8* wpL2    = (bf16x8*)alloc(2048 * 16);

    (void)hipMemsetAsync(gtail, 0, NBUK * 4, stream);
    // wpack(W1) | wpack(W2) | pass A bucket binning
    k1<<<K1_GRID, 256, 0, stream>>>(W1, wpH1, wpL1, W2, wpH2, wpL2,
                                    dst, src, gtail, tmp);
    // pass B (CSR in LDS) | gemm1
    k2<<<K2_GRID, 256, 0, stream>>>(x, wpH1, wpL1, as1, ad1, hb, a_src, a_dst,
                                    gtail, tmp, row_ptr, src_sorted);
    // agg layer 1 + fused gemm2 (2-wave coupling)
    k_ag1<<<AG1_GRID, 128, 0, stream>>>((const u32*)hb, a_src, a_dst, row_ptr,
                                        src_sorted, b1, wpH2, wpL2, as2, ad2,
                                        x1b, hb2, a_src2, a_dst2);
    // agg layer 2 -> final interleaved output
    k_agg2<<<AGG2_GRID, 256, 0, stream>>>((const u32*)hb2, a_src2, a_dst2,
                                          row_ptr, src_sorted, b2,
                                          (const u32*)x1b, out);
}

// Round 22
// 248.192 us; speedup vs baseline: 1.2397x; 1.0763x over previous
//
#include <hip/hip_runtime.h>

#define NN 100000
#define NE 1600000
#define GEMM_GRID 1563            // ceil(NN/64)
#define NBUK 391                  // dst buckets of 256 nodes
#define BCAP 5120                 // per-bucket capacity (mean 4092, +16 sigma)
#define PA_BLOCKS 320             // pass A blocks, 5000 edges each
#define PA_EDGES 5000
#define K1_GRID (16 + PA_BLOCKS)
#define K2_GRID (NBUK + GEMM_GRID)
#define AG1_GRID 6250             // 16 nodes/block (4 waves x 4)
#define AGG2_GRID 12500           // 8 nodes/block (4 waves x 2)

typedef short bf16x8 __attribute__((ext_vector_type(8)));
typedef float f32x4 __attribute__((ext_vector_type(4)));
typedef unsigned int u32;
typedef u32 u32x4 __attribute__((ext_vector_type(4)));
typedef unsigned short u16;

__device__ inline u32 bf16r(float x) {  // RTNE bf16, returns low-16 bits
    u32 u = __float_as_uint(x);
    return (u + 0x7FFFu + ((u >> 16) & 1u)) >> 16;
}

// ---------------- split-bf16 helpers ----------------
__device__ inline void split_pack8(const float a[8], u32 hh[4], u32 ll[4]) {
#pragma unroll
    for (int j = 0; j < 4; ++j) {
        u32 u0 = __float_as_uint(a[2 * j]);
        u32 u1 = __float_as_uint(a[2 * j + 1]);
        float l0 = a[2 * j] - __uint_as_float(u0 & 0xFFFF0000u);
        float l1 = a[2 * j + 1] - __uint_as_float(u1 & 0xFFFF0000u);
        hh[j] = (u0 >> 16) | (u1 & 0xFFFF0000u);
        ll[j] = (__float_as_uint(l0) >> 16) | (__float_as_uint(l1) & 0xFFFF0000u);
    }
}

__device__ inline void wpack_body(int idx, const float* __restrict__ W,
                                  bf16x8* __restrict__ wpH, bf16x8* __restrict__ wpL) {
    if (idx >= 2048) return;
    int lane = idx & 63, tile = idx >> 6;
    int kc = tile >> 3, ct = tile & 7;
    int col = lane & 15, kq = lane >> 4;
    int kbase = kc * 32 + kq * 8;
    float a[8];
#pragma unroll
    for (int i = 0; i < 8; ++i)
        a[i] = W[(size_t)(kbase + i) * 128 + ct * 16 + col];
    u32 hh[4], ll[4];
    split_pack8(a, hh, ll);
    wpH[tile * 64 + lane] = __builtin_bit_cast(bf16x8, (u32x4){hh[0], hh[1], hh[2], hh[3]});
    wpL[tile * 64 + lane] = __builtin_bit_cast(bf16x8, (u32x4){ll[0], ll[1], ll[2], ll[3]});
}

// ---------------- k1: wpack(W1) | wpack(W2) | pass A bucket binning ---------
__global__ __launch_bounds__(256) void k1(
    const float* __restrict__ W1, bf16x8* __restrict__ wpH1, bf16x8* __restrict__ wpL1,
    const float* __restrict__ W2, bf16x8* __restrict__ wpH2, bf16x8* __restrict__ wpL2,
    const int* __restrict__ dst, const int* __restrict__ src,
    int* __restrict__ gtail, u32* __restrict__ tmp) {
    const int b = blockIdx.x;
    if (b < 8) {
        wpack_body(b * 256 + threadIdx.x, W1, wpH1, wpL1);
        return;
    } else if (b < 16) {
        wpack_body((b - 8) * 256 + threadIdx.x, W2, wpH2, wpL2);
        return;
    }
    __shared__ int lhist[NBUK], lcur[NBUK];
    const int t = threadIdx.x;
    const int e0 = (b - 16) * PA_EDGES;
    const int e1 = e0 + PA_EDGES;  // PA_BLOCKS*PA_EDGES == NE exactly
    for (int i = t; i < NBUK; i += 256) lhist[i] = 0;
    __syncthreads();
    for (int e = e0 + t; e < e1; e += 256)
        atomicAdd(&lhist[dst[e] >> 8], 1);
    __syncthreads();
    for (int i = t; i < NBUK; i += 256)
        if (lhist[i] > 0) lcur[i] = atomicAdd(&gtail[i], lhist[i]);
    __syncthreads();
    for (int e = e0 + t; e < e1; e += 256) {
        int d = dst[e];
        int bb = d >> 8;
        int p = atomicAdd(&lcur[bb], 1);
        tmp[(size_t)bb * BCAP + p] = ((u32)(d & 255) << 17) | (u32)src[e];
    }
}

// shared GEMM epilogue (gemm1): h (bf16, node-major) + attention logits
__device__ inline void gemm_epilogue(f32x4 acc[8], int row0, int w, int col, int kq,
                                     const float* __restrict__ atts,
                                     const float* __restrict__ attd,
                                     u16* __restrict__ hb,
                                     float* __restrict__ a_src,
                                     float* __restrict__ a_dst) {
    float as0[4], as1[4], ad0[4], ad1[4];
#pragma unroll
    for (int q = 0; q < 4; ++q) {
        as0[q] = atts[q * 32 + col];
        as1[q] = atts[q * 32 + 16 + col];
        ad0[q] = attd[q * 32 + col];
        ad1[q] = attd[q * 32 + 16 + col];
    }
#pragma unroll
    for (int r = 0; r < 4; ++r) {
        int node = row0 + w * 16 + kq * 4 + r;
        float ps[4], pd[4];
#pragma unroll
        for (int q = 0; q < 4; ++q) {
            float d0 = acc[2 * q][r], d1 = acc[2 * q + 1][r];
            ps[q] = d0 * as0[q] + d1 * as1[q];
            pd[q] = d0 * ad0[q] + d1 * ad1[q];
        }
#pragma unroll
        for (int off = 1; off < 16; off <<= 1) {
#pragma unroll
            for (int q = 0; q < 4; ++q) {
                ps[q] += __shfl_xor(ps[q], off);
                pd[q] += __shfl_xor(pd[q], off);
            }
        }
        if (node < NN) {
#pragma unroll
            for (int ct = 0; ct < 8; ++ct)
                hb[(size_t)node * 128 + ct * 16 + col] = (u16)bf16r(acc[ct][r]);
            if (col < 4) {
                float vs = col == 0 ? ps[0] : col == 1 ? ps[1] : col == 2 ? ps[2] : ps[3];
                float vd = col == 0 ? pd[0] : col == 1 ? pd[1] : col == 2 ? pd[2] : pd[3];
                a_src[node * 4 + col] = vs;
                a_dst[node * 4 + col] = vd;
            }
        }
    }
}

// ---------------- k2: pass B (CSR build in LDS, blocks 0..390) | gemm1 ------
__global__ __launch_bounds__(256) void k2(
    const float* __restrict__ x,
    const bf16x8* __restrict__ wpH, const bf16x8* __restrict__ wpL,
    const float* __restrict__ atts, const float* __restrict__ attd,
    u16* __restrict__ hb, float* __restrict__ a_src, float* __restrict__ a_dst,
    const int* __restrict__ gtail, const u32* __restrict__ tmp,
    int* __restrict__ row_ptr, int* __restrict__ src_sorted) {
    __shared__ u32 ldata[BCAP];     // 20 KB
    __shared__ int lh[256];         // hist -> cursors
    __shared__ int lsc[256];        // scan / reduce workspace
    const int idx = blockIdx.x;
    const int t = threadIdx.x;
    if (idx < NBUK) {
        const int g = idx;
        const int n = gtail[g];
        int acc = 0;
        for (int i = t; i < g; i += 256) acc += gtail[i];
        lsc[t] = acc;
        __syncthreads();
        for (int off = 128; off > 0; off >>= 1) {
            if (t < off) lsc[t] += lsc[t + off];
            __syncthreads();
        }
        const int ebase = lsc[0];
        lh[t] = 0;
        __syncthreads();
        for (int i = t; i < n; i += 256) {
            u32 v = tmp[(size_t)g * BCAP + i];
            ldata[i] = v;
            atomicAdd(&lh[v >> 17], 1);
        }
        __syncthreads();
        int c = lh[t];
        lsc[t] = c;
        __syncthreads();
        for (int off = 1; off < 256; off <<= 1) {
            int xv = (t >= off) ? lsc[t - off] : 0;
            __syncthreads();
            lsc[t] += xv;
            __syncthreads();
        }
        int excl = (t == 0) ? 0 : lsc[t - 1];
        int base = ebase + excl;
        lh[t] = base;
        int node = (g << 8) + t;
        if (node < NN) row_ptr[node] = base;
        if (g == NBUK - 1 && t == 0) row_ptr[NN] = ebase + n;
        __syncthreads();
        for (int i = t; i < n; i += 256) {
            u32 v = ldata[i];
            int p = atomicAdd(&lh[v >> 17], 1);
            src_sorted[p] = (int)(v & 0x1FFFFu);
        }
        return;
    }
    const int row0 = (idx - NBUK) * 64;
    const int lane = t & 63;
    const int w = t >> 6;
    const int col = lane & 15, kq = lane >> 4;
    int node_a = row0 + w * 16 + col;
    if (node_a > NN - 1) node_a = NN - 1;
    const float* xrow = x + (size_t)node_a * 128 + kq * 8;
    float a[32];
#pragma unroll
    for (int kc = 0; kc < 4; ++kc) {
        *(float4*)&a[kc * 8 + 0] = *(const float4*)(xrow + kc * 32);
        *(float4*)&a[kc * 8 + 4] = *(const float4*)(xrow + kc * 32 + 4);
    }
    f32x4 acc[8];
#pragma unroll
    for (int ct = 0; ct < 8; ++ct) acc[ct] = (f32x4){0.f, 0.f, 0.f, 0.f};
#pragma unroll
    for (int kc = 0; kc < 4; ++kc) {
        u32 hh[4], ll[4];
        split_pack8(&a[kc * 8], hh, ll);
        bf16x8 ah = __builtin_bit_cast(bf16x8, (u32x4){hh[0], hh[1], hh[2], hh[3]});
        bf16x8 al = __builtin_bit_cast(bf16x8, (u32x4){ll[0], ll[1], ll[2], ll[3]});
#pragma unroll
        for (int ct = 0; ct < 8; ++ct) {
            bf16x8 bh = wpH[(kc * 8 + ct) * 64 + lane];
            bf16x8 bl = wpL[(kc * 8 + ct) * 64 + lane];
            acc[ct] = __builtin_amdgcn_mfma_f32_16x16x32_bf16(ah, bh, acc[ct], 0, 0, 0);
            acc[ct] = __builtin_amdgcn_mfma_f32_16x16x32_bf16(al, bh, acc[ct], 0, 0, 0);
            acc[ct] = __builtin_amdgcn_mfma_f32_16x16x32_bf16(ah, bl, acc[ct], 0, 0, 0);
        }
    }
    gemm_epilogue(acc, row0, w, col, kq, atts, attd, hb, a_src, a_dst);
}

// ------ k_ag1: agg layer 1 (16 nodes/block) + fused gemm2 for those nodes ---
// Stage 1: proven gather body, 4 nodes/wave; x1 rows -> LDS (+x1b for agg2's
// interleave). Stage 2: one 16-row MFMA tile; wave w owns cts {2w,2w+1} =
// head w -> logit epilogue is wave-local. Layer-2 outputs go to hb2/a_*2
// (separate buffers: other blocks still gather layer-1 data).
__global__ __launch_bounds__(256) void k_ag1(
    const u32* __restrict__ hb,
    const float* __restrict__ a_src, const float* __restrict__ a_dst,
    const int* __restrict__ row_ptr, const int* __restrict__ src_sorted,
    const float* __restrict__ bias1,
    const bf16x8* __restrict__ wpH2, const bf16x8* __restrict__ wpL2,
    const float* __restrict__ atts2, const float* __restrict__ attd2,
    u32* __restrict__ x1b, u16* __restrict__ hb2,
    float* __restrict__ a_src2, float* __restrict__ a_dst2) {
    __shared__ __align__(16) u32 xs[16][68];
    const int t = threadIdx.x;
    const int lane = t & 63;
    const int wv = t >> 6;
    const int q = lane >> 4;
    const int es = lane & 15;
    const int hbase = lane & 48;
    const int node0 = blockIdx.x * 16;
    const float bv0 = bias1[lane * 2], bv1 = bias1[lane * 2 + 1];
    // ---------------- stage 1: aggregate layer 1 ----------------
#pragma unroll 1
    for (int ni = 0; ni < 4; ++ni) {
        const int node = node0 + wv * 4 + ni;   // NN = 6250*16 exactly
        const int e0 = row_ptr[node], e1 = row_ptr[node + 1];
        const int emax = e1 - 1;
        const float advh = a_dst[node * 4 + q];
        float den = 0.f, a0a = 0.f, a0b = 0.f, a1a = 0.f, a1b = 0.f;
        if (e1 > e0) {
            int eidx = e0 + es;
            if (eidx > emax) eidx = emax;
            int sv = src_sorted[eidx];
            float av = a_src[sv * 4 + q];
            for (int ec = e0; ec < e1; ec += 16) {
                int cnt = e1 - ec;
                cnt = cnt < 16 ? cnt : 16;
                int eidxn = ec + 16 + es;
                if (eidxn > emax) eidxn = emax;
                int svn = src_sorted[eidxn];
                float avn = a_src[svn * 4 + q];
                float lk = av + advh;
                lk = lk > 0.f ? lk : 0.2f * lk;
                float ex = (es < cnt) ? __expf(lk - 8.f) : 0.f;
                den += ex;
                if (cnt == 16) {
                    u32 wvv[16];
#pragma unroll
                    for (int u = 0; u < 16; ++u) {
                        int su = __builtin_amdgcn_readlane(sv, u);
                        wvv[u] = hb[((size_t)su << 6) + lane];
                    }
                    float exu[16];
#pragma unroll
                    for (int u = 0; u < 16; ++u) exu[u] = __shfl(ex, hbase | u);
#pragma unroll
                    for (int u = 0; u < 16; ++u) {
                        float h0 = __uint_as_float(wvv[u] << 16);
                        float h1 = __uint_as_float(wvv[u] & 0xFFFF0000u);
                        if (u & 1) { a0b = fmaf(exu[u], h0, a0b); a1b = fmaf(exu[u], h1, a1b); }
                        else       { a0a = fmaf(exu[u], h0, a0a); a1a = fmaf(exu[u], h1, a1a); }
                    }
                } else {
                    for (int u0 = 0; u0 < cnt; u0 += 4) {
                        u32 wvv[4];
                        float exu[4];
#pragma unroll
                        for (int j = 0; j < 4; ++j) {
                            int su = __builtin_amdgcn_readlane(sv, u0 + j);
                            wvv[j] = hb[((size_t)su << 6) + lane];
                        }
#pragma unroll
                        for (int j = 0; j < 4; ++j) exu[j] = __shfl(ex, hbase | (u0 + j));
#pragma unroll
                        for (int j = 0; j < 4; ++j) {
                            float h0 = __uint_as_float(wvv[j] << 16);
                            float h1 = __uint_as_float(wvv[j] & 0xFFFF0000u);
                            if (j & 1) { a0b = fmaf(exu[j], h0, a0b); a1b = fmaf(exu[j], h1, a1b); }
                            else       { a0a = fmaf(exu[j], h0, a0a); a1a = fmaf(exu[j], h1, a1a); }
                        }
                    }
                }
                sv = svn;
                av = avn;
            }
        }
        float a0 = a0a + a0b, a1 = a1a + a1b;
#pragma unroll
        for (int m = 1; m < 16; m <<= 1) den += __shfl_xor(den, m);
        float inv = den > 0.f ? 1.f / den : 0.f;
        float r0 = fmaxf(fmaf(a0, inv, bv0), 0.f);
        float r1 = fmaxf(fmaf(a1, inv, bv1), 0.f);
        u32 pair = bf16r(r0) | (bf16r(r1) << 16);
        x1b[node * 64 + lane] = pair;
        xs[wv * 4 + ni][lane] = pair;
    }
    __syncthreads();
    // ---------------- stage 2: gemm2 for the block's 16 nodes ----------------
    const int col = lane & 15, kq = lane >> 4;
    const int ct0 = 2 * wv, ct1 = 2 * wv + 1;
    int4 aw[4];
#pragma unroll
    for (int kc = 0; kc < 4; ++kc)
        aw[kc] = *(const int4*)&xs[col][kc * 16 + kq * 4];
    f32x4 acc0 = (f32x4){0.f, 0.f, 0.f, 0.f};
    f32x4 acc1 = (f32x4){0.f, 0.f, 0.f, 0.f};
#pragma unroll
    for (int kc = 0; kc < 4; ++kc) {
        bf16x8 a = __builtin_bit_cast(bf16x8, aw[kc]);
        acc0 = __builtin_amdgcn_mfma_f32_16x16x32_bf16(a, wpH2[(kc * 8 + ct0) * 64 + lane], acc0, 0, 0, 0);
        acc0 = __builtin_amdgcn_mfma_f32_16x16x32_bf16(a, wpL2[(kc * 8 + ct0) * 64 + lane], acc0, 0, 0, 0);
        acc1 = __builtin_amdgcn_mfma_f32_16x16x32_bf16(a, wpH2[(kc * 8 + ct1) * 64 + lane], acc1, 0, 0, 0);
        acc1 = __builtin_amdgcn_mfma_f32_16x16x32_bf16(a, wpL2[(kc * 8 + ct1) * 64 + lane], acc1, 0, 0, 0);
    }
    const float as0 = atts2[wv * 32 + col], as1 = atts2[wv * 32 + 16 + col];
    const float ad0 = attd2[wv * 32 + col], ad1 = attd2[wv * 32 + 16 + col];
#pragma unroll
    for (int r = 0; r < 4; ++r) {
        int node = node0 + kq * 4 + r;
        float d0 = acc0[r], d1 = acc1[r];
        float ps = d0 * as0 + d1 * as1;
        float pd = d0 * ad0 + d1 * ad1;
#pragma unroll
        for (int off = 1; off < 16; off <<= 1) {
            ps += __shfl_xor(ps, off);
            pd += __shfl_xor(pd, off);
        }
        hb2[(size_t)node * 128 + ct0 * 16 + col] = (u16)bf16r(d0);
        hb2[(size_t)node * 128 + ct1 * 16 + col] = (u16)bf16r(d1);
        if (col == 0) {
            a_src2[node * 4 + wv] = ps;
            a_dst2[node * 4 + wv] = pd;
        }
    }
}

// ---------------- k_agg2: layer-2 aggregation (r16 proven body) --------------
__global__ __launch_bounds__(256, 4) void k_agg2(
    const u32* __restrict__ hb,
    const float* __restrict__ a_src, const float* __restrict__ a_dst,
    const int* __restrict__ row_ptr, const int* __restrict__ src_sorted,
    const float* __restrict__ bias,
    const u32* __restrict__ x1b, float* __restrict__ outp) {
    const int lane = threadIdx.x & 63;
    const int node0 = blockIdx.x * 8 + (threadIdx.x >> 6) * 2;
    const int q = lane >> 4;
    const int es = lane & 15;
    const int hbase = lane & 48;
#pragma unroll
    for (int ni = 0; ni < 2; ++ni) {
        const int node = node0 + ni;
        if (node >= NN) continue;
        const int e0 = row_ptr[node], e1 = row_ptr[node + 1];
        const int emax = e1 - 1;
        const float advh = a_dst[node * 4 + q];
        float den = 0.f, a0a = 0.f, a0b = 0.f, a1a = 0.f, a1b = 0.f;
        if (e1 > e0) {
            int eidx = e0 + es;
            if (eidx > emax) eidx = emax;
            int sv = src_sorted[eidx];
            float av = a_src[sv * 4 + q];
            for (int ec = e0; ec < e1; ec += 16) {
                int cnt = e1 - ec;
                cnt = cnt < 16 ? cnt : 16;
                int eidxn = ec + 16 + es;
                if (eidxn > emax) eidxn = emax;
                int svn = src_sorted[eidxn];
                float avn = a_src[svn * 4 + q];
                float lk = av + advh;
                lk = lk > 0.f ? lk : 0.2f * lk;
                float ex = (es < cnt) ? __expf(lk - 8.f) : 0.f;
                den += ex;
                if (cnt == 16) {
                    u32 wv[16];
#pragma unroll
                    for (int u = 0; u < 16; ++u) {
                        int su = __builtin_amdgcn_readlane(sv, u);
                        wv[u] = hb[((size_t)su << 6) + lane];
                    }
                    float exu[16];
#pragma unroll
                    for (int u = 0; u < 16; ++u) exu[u] = __shfl(ex, hbase | u);
#pragma unroll
                    for (int u = 0; u < 16; ++u) {
                        float h0 = __uint_as_float(wv[u] << 16);
                        float h1 = __uint_as_float(wv[u] & 0xFFFF0000u);
                        if (u & 1) { a0b = fmaf(exu[u], h0, a0b); a1b = fmaf(exu[u], h1, a1b); }
                        else       { a0a = fmaf(exu[u], h0, a0a); a1a = fmaf(exu[u], h1, a1a); }
                    }
                } else {
                    for (int u0 = 0; u0 < cnt; u0 += 4) {
                        u32 wv[4];
                        float exu[4];
#pragma unroll
                        for (int j = 0; j < 4; ++j) {
                            int su = __builtin_amdgcn_readlane(sv, u0 + j);
                            wv[j] = hb[((size_t)su << 6) + lane];
                        }
#pragma unroll
                        for (int j = 0; j < 4; ++j) exu[j] = __shfl(ex, hbase | (u0 + j));
#pragma unroll
                        for (int j = 0; j < 4; ++j) {
                            float h0 = __uint_as_float(wv[j] << 16);
                            float h1 = __uint_as_float(wv[j] & 0xFFFF0000u);
                            if (j & 1) { a0b = fmaf(exu[j], h0, a0b); a1b = fmaf(exu[j], h1, a1b); }
                            else       { a0a = fmaf(exu[j], h0, a0a); a1a = fmaf(exu[j], h1, a1a); }
                        }
                    }
                }
                sv = svn;
                av = avn;
            }
        }
        float a0 = a0a + a0b, a1 = a1a + a1b;
#pragma unroll
        for (int m = 1; m < 16; m <<= 1) den += __shfl_xor(den, m);
        float inv = den > 0.f ? 1.f / den : 0.f;
        int c0 = lane * 2;
        float r0 = fmaxf(fmaf(a0, inv, bias[c0]), 0.f);
        float r1 = fmaxf(fmaf(a1, inv, bias[c0 + 1]), 0.f);
        u32 w1 = x1b[node * 64 + lane];
        float4 o;
        o.x = __uint_as_float(w1 << 16);          // x1[2l]
        o.y = r0;                                  // x2[2l]
        o.z = __uint_as_float(w1 & 0xFFFF0000u);  // x1[2l+1]
        o.w = r1;                                  // x2[2l+1]
        u32x4 ov = __builtin_bit_cast(u32x4, o);
        __builtin_nontemporal_store(ov,
            (u32x4*)(outp + (size_t)node * 256 + lane * 4));
    }
}

// ---------------- launch ----------------

extern "C" void kernel_launch(void* const* d_in, const int* in_sizes, int n_in,
                              void* d_out, int out_size, void* d_ws, size_t ws_size,
                              hipStream_t stream) {
    const float* x   = (const float*)d_in[0];
    const int*   ei  = (const int*)d_in[1];
    const float* W1  = (const float*)d_in[2];
    const float* as1 = (const float*)d_in[3];
    const float* ad1 = (const float*)d_in[4];
    const float* b1  = (const float*)d_in[5];
    const float* W2  = (const float*)d_in[6];
    const float* as2 = (const float*)d_in[7];
    const float* ad2 = (const float*)d_in[8];
    const float* b2  = (const float*)d_in[9];
    float* out = (float*)d_out;
    const int* src = ei;
    const int* dst = ei + NE;

    char* w = (char*)d_ws;
    size_t off = 0;
    auto alloc = [&](size_t bytes) -> void* {
        void* p = w + off;
        off = (off + bytes + 255) & ~((size_t)255);
        return p;
    };
    u16* hb         = (u16*)alloc((size_t)NN * 128 * 2);   // layer-1 h (bf16)
    u16* hb2        = (u16*)alloc((size_t)NN * 128 * 2);   // layer-2 h (bf16)
    u32* x1b        = (u32*)alloc((size_t)NN * 64 * 4);    // x1 as bf16 pairs
    float* a_src    = (float*)alloc((size_t)NN * 4 * 4);
    float* a_dst    = (float*)alloc((size_t)NN * 4 * 4);
    float* a_src2   = (float*)alloc((size_t)NN * 4 * 4);
    float* a_dst2   = (float*)alloc((size_t)NN * 4 * 4);
    int* row_ptr    = (int*)alloc((size_t)(NN + 1) * 4);
    int* gtail      = (int*)alloc(NBUK * 4);
    u32* tmp        = (u32*)alloc((size_t)NBUK * BCAP * 4);
    int* src_sorted = (int*)alloc((size_t)NE * 4);
    bf16x8* wpH1    = (bf16x8*)alloc(2048 * 16);
    bf16x8* wpL1    = (bf16x8*)alloc(2048 * 16);
    bf16x8* wpH2    = (bf16x8*)alloc(2048 * 16);
    bf16x8* wpL2    = (bf16x8*)alloc(2048 * 16);

    (void)hipMemsetAsync(gtail, 0, NBUK * 4, stream);
    // wpack(W1) | wpack(W2) | pass A bucket binning
    k1<<<K1_GRID, 256, 0, stream>>>(W1, wpH1, wpL1, W2, wpH2, wpL2,
                                    dst, src, gtail, tmp);
    // pass B (CSR in LDS) | gemm1
    k2<<<K2_GRID, 256, 0, stream>>>(x, wpH1, wpL1, as1, ad1, hb, a_src, a_dst,
                                    gtail, tmp, row_ptr, src_sorted);
    // agg layer 1 + fused gemm2
    k_ag1<<<AG1_GRID, 256, 0, stream>>>((const u32*)hb, a_src, a_dst, row_ptr,
                                        src_sorted, b1, wpH2, wpL2, as2, ad2,
                                        x1b, hb2, a_src2, a_dst2);
    // agg layer 2 -> final interleaved output
    k_agg2<<<AGG2_GRID, 256, 0, stream>>>((const u32*)hb2, a_src2, a_dst2,
                                          row_ptr, src_sorted, b2,
                                          (const u32*)x1b, out);
}